// Round 1
// baseline (30.573 us; speedup 1.0000x reference)
//
#include <hip/hip_runtime.h>

#define EPS    1e-5f
#define NSLOPE 0.01f
#define B 4
#define N 256
#define F 128

// workspace float layout
#define WS_WE0 0        // we0[g]*s1[g]           (128)
#define WS_WE1 128      // we1[g]*s1[g]           (128)
#define WS_PF0 256      // weff[0][g]             (128)
#define WS_PF1 384      // weff[1][g]             (128)
#define WS_C   512      // c[0..1]                (2, padded)
#define WS_S1  520      // s1[g]                  (128)
#define WS_T1  648      // t1[g]                  (128)
#define WS_HL  1024     // hl''[b,i,g] = hl*s1+t1 (B*N*F)
#define WS_HR  (1024 + B*N*F)  // hr'[b,j,g] = hr*s1 (B*N*F)

// ---------------------------------------------------------------- prep0
// One block of 128 threads: fold all the affine tails/heads.
__global__ __launch_bounds__(128) void prep0(
    const float* __restrict__ w1,
    const float* __restrict__ g1, const float* __restrict__ b1,
    const float* __restrict__ m1, const float* __restrict__ v1,
    const float* __restrict__ w2,
    const float* __restrict__ g2, const float* __restrict__ b2,
    const float* __restrict__ m2, const float* __restrict__ v2,
    const float* __restrict__ pw, const float* __restrict__ pb,
    float* __restrict__ ws) {
  __shared__ float s2s[F], t2s[F];
  int g = threadIdx.x;
  float s1v = g1[g] / sqrtf(v1[g] + EPS);
  ws[WS_S1 + g] = s1v;
  ws[WS_T1 + g] = b1[g] - m1[g] * s1v;
  ws[WS_WE0 + g] = w1[g * 258 + 0] * s1v;
  ws[WS_WE1 + g] = w1[g * 258 + 1] * s1v;
  float s2v = g2[g] / sqrtf(v2[g] + EPS);
  s2s[g] = s2v;
  t2s[g] = b2[g] - m2[g] * s2v;
  __syncthreads();
  float a0 = 0.f, a1 = 0.f;
  for (int f = 0; f < F; ++f) {
    float wv = w2[f * F + g];                 // coalesced (g fastest)
    a0 = fmaf(pw[f]     * s2s[f], wv, a0);
    a1 = fmaf(pw[F + f] * s2s[f], wv, a1);
  }
  ws[WS_PF0 + g] = a0;
  ws[WS_PF1 + g] = a1;
  if (g < 2) {
    float c = pb[g];
    for (int f = 0; f < F; ++f) c += pw[g * F + f] * t2s[f];
    ws[WS_C + g] = c;
  }
}

// ---------------------------------------------------------------- prep1
// hl''[row,g] and hr'[row,g] for all 1024 node rows.
// grid 128 blocks x 128 threads; each block does 8 rows, thread = g.
__global__ __launch_bounds__(128) void prep1(
    const float* __restrict__ node, const float* __restrict__ w1,
    float* __restrict__ ws) {
  __shared__ float ns[8][F];
  int tid = threadIdx.x;
  int r0 = blockIdx.x * 8;
  {
    int r = tid >> 4, c = (tid & 15) * 8;
    const float* src = node + (size_t)(r0 + r) * F + c;
    *reinterpret_cast<float4*>(&ns[r][c])     = *reinterpret_cast<const float4*>(src);
    *reinterpret_cast<float4*>(&ns[r][c + 4]) = *reinterpret_cast<const float4*>(src + 4);
  }
  __syncthreads();
  int g = tid;
  float accl[8] = {0.f, 0.f, 0.f, 0.f, 0.f, 0.f, 0.f, 0.f};
  float accr[8] = {0.f, 0.f, 0.f, 0.f, 0.f, 0.f, 0.f, 0.f};
  for (int f = 0; f < F; ++f) {
    float wl = w1[g * 258 + 2 + f];        // L1/L2-resident (132 KB total)
    float wr = w1[g * 258 + 130 + f];
    #pragma unroll
    for (int r = 0; r < 8; ++r) {
      float nv = ns[r][f];                 // LDS broadcast
      accl[r] = fmaf(nv, wl, accl[r]);
      accr[r] = fmaf(nv, wr, accr[r]);
    }
  }
  float s1v = ws[WS_S1 + g], t1v = ws[WS_T1 + g];
  float* hl = ws + WS_HL;
  float* hr = ws + WS_HR;
  #pragma unroll
  for (int r = 0; r < 8; ++r) {
    hl[(size_t)(r0 + r) * F + g] = fmaf(accl[r], s1v, t1v);  // t1 folded here only
    hr[(size_t)(r0 + r) * F + g] = accr[r] * s1v;
  }
}

// ---------------------------------------------------------------- main
// grid (N/16, N/16, B), block 256 = 16x16 (i,j) tile.
__global__ __launch_bounds__(256) void fused_main(
    const float* __restrict__ edge,
    const float* __restrict__ ws, float* __restrict__ out) {
  __shared__ float hls[16][132];   // +4 pad keeps float4 alignment, banks spread
  __shared__ float hrs[16][132];
  int b = blockIdx.z, i0 = blockIdx.y * 16, j0 = blockIdx.x * 16;
  int tid = threadIdx.x;
  const float* hl = ws + WS_HL;
  const float* hr = ws + WS_HR;
  {
    int r = tid >> 4, c = (tid & 15) * 8;
    const float* sl = hl + (size_t)(b * N + i0 + r) * F + c;
    const float* sr = hr + (size_t)(b * N + j0 + r) * F + c;
    *reinterpret_cast<float4*>(&hls[r][c])     = *reinterpret_cast<const float4*>(sl);
    *reinterpret_cast<float4*>(&hls[r][c + 4]) = *reinterpret_cast<const float4*>(sl + 4);
    *reinterpret_cast<float4*>(&hrs[r][c])     = *reinterpret_cast<const float4*>(sr);
    *reinterpret_cast<float4*>(&hrs[r][c + 4]) = *reinterpret_cast<const float4*>(sr + 4);
  }
  __syncthreads();
  int ti = tid >> 4, tj = tid & 15;
  size_t eidx = ((size_t)(b * N + i0 + ti) * N + (j0 + tj)) * 2;
  float2 e = *reinterpret_cast<const float2*>(edge + eidx);
  float acc0 = 0.f, acc1 = 0.f;
  #pragma unroll 8
  for (int g = 0; g < F; g += 4) {
    float4 L  = *reinterpret_cast<const float4*>(&hls[ti][g]);
    float4 R  = *reinterpret_cast<const float4*>(&hrs[tj][g]);
    float4 W0 = *reinterpret_cast<const float4*>(ws + WS_WE0 + g);  // uniform -> s_load
    float4 W1 = *reinterpret_cast<const float4*>(ws + WS_WE1 + g);
    float4 P0 = *reinterpret_cast<const float4*>(ws + WS_PF0 + g);
    float4 P1 = *reinterpret_cast<const float4*>(ws + WS_PF1 + g);
    float v, a;
    v = L.x + R.x; v = fmaf(e.x, W0.x, v); v = fmaf(e.y, W1.x, v);
    a = v >= 0.f ? v : NSLOPE * v;
    acc0 = fmaf(P0.x, a, acc0); acc1 = fmaf(P1.x, a, acc1);
    v = L.y + R.y; v = fmaf(e.x, W0.y, v); v = fmaf(e.y, W1.y, v);
    a = v >= 0.f ? v : NSLOPE * v;
    acc0 = fmaf(P0.y, a, acc0); acc1 = fmaf(P1.y, a, acc1);
    v = L.z + R.z; v = fmaf(e.x, W0.z, v); v = fmaf(e.y, W1.z, v);
    a = v >= 0.f ? v : NSLOPE * v;
    acc0 = fmaf(P0.z, a, acc0); acc1 = fmaf(P1.z, a, acc1);
    v = L.w + R.w; v = fmaf(e.x, W0.w, v); v = fmaf(e.y, W1.w, v);
    a = v >= 0.f ? v : NSLOPE * v;
    acc0 = fmaf(P0.w, a, acc0); acc1 = fmaf(P1.w, a, acc1);
  }
  float2 o;
  o.x = acc0 + ws[WS_C + 0];
  o.y = acc1 + ws[WS_C + 1];
  *reinterpret_cast<float2*>(out + eidx) = o;
}

extern "C" void kernel_launch(void* const* d_in, const int* in_sizes, int n_in,
                              void* d_out, int out_size, void* d_ws, size_t ws_size,
                              hipStream_t stream) {
  const float* node = (const float*)d_in[0];
  const float* edge = (const float*)d_in[1];
  const float* w1   = (const float*)d_in[2];
  const float* g1   = (const float*)d_in[3];
  const float* b1   = (const float*)d_in[4];
  const float* m1   = (const float*)d_in[5];
  const float* v1   = (const float*)d_in[6];
  const float* w2   = (const float*)d_in[7];
  const float* g2   = (const float*)d_in[8];
  const float* b2   = (const float*)d_in[9];
  const float* m2   = (const float*)d_in[10];
  const float* v2   = (const float*)d_in[11];
  const float* pw   = (const float*)d_in[12];
  const float* pb   = (const float*)d_in[13];
  float* ws  = (float*)d_ws;
  float* out = (float*)d_out;

  prep0<<<1, 128, 0, stream>>>(w1, g1, b1, m1, v1, w2, g2, b2, m2, v2, pw, pb, ws);
  prep1<<<128, 128, 0, stream>>>(node, w1, ws);
  fused_main<<<dim3(N / 16, N / 16, B), 256, 0, stream>>>(edge, ws, out);
}